// Round 11
// baseline (368.038 us; speedup 1.0000x reference)
//
#include <hip/hip_runtime.h>
#include <hip/hip_bf16.h>

#define NEGV (-10000.0f)
constexpr int B_ = 32, S_ = 256, D_ = 512, K_ = 8, L_ = 64;

typedef __bf16 bf16_t;
typedef bf16_t bf16x8 __attribute__((ext_vector_type(8)));
typedef float f32x4 __attribute__((ext_vector_type(4)));

__device__ __forceinline__ float u2f(unsigned int u) {
  union { unsigned int u; float f; } x; x.u = u; return x.f;
}
__device__ __forceinline__ unsigned int f2bfbits(float f) {
  union { bf16_t h; unsigned short u; } x; x.h = (bf16_t)f; return (unsigned int)x.u;
}

// ---------------------------------------------------------------------------
// cast word_rep -> bf16 Awr [8192][512]; blocks >= 2048 cast cls_w -> bf16.
// ---------------------------------------------------------------------------
__global__ __launch_bounds__(256) void cast_kernel(const float* __restrict__ wr,
                                                   bf16_t* __restrict__ Awr,
                                                   const float* __restrict__ cls_w,
                                                   bf16_t* __restrict__ clsb) {
  const int bid = blockIdx.x;
  if (bid < 2048) {
    const int i = (bid * 256 + threadIdx.x) * 8;
    const float4 a = *(const float4*)(wr + i);
    const float4 b = *(const float4*)(wr + i + 4);
    bf16x8 o;
    o[0] = (bf16_t)a.x; o[1] = (bf16_t)a.y; o[2] = (bf16_t)a.z; o[3] = (bf16_t)a.w;
    o[4] = (bf16_t)b.x; o[5] = (bf16_t)b.y; o[6] = (bf16_t)b.z; o[7] = (bf16_t)b.w;
    *(bf16x8*)(Awr + i) = o;
  } else {
    const int i = ((bid - 2048) * 256 + threadIdx.x) * 8;
    const float4 a = *(const float4*)(cls_w + i);
    const float4 b = *(const float4*)(cls_w + i + 4);
    bf16x8 o;
    o[0] = (bf16_t)a.x; o[1] = (bf16_t)a.y; o[2] = (bf16_t)a.z; o[3] = (bf16_t)a.w;
    o[4] = (bf16_t)b.x; o[5] = (bf16_t)b.y; o[6] = (bf16_t)b.z; o[7] = (bf16_t)b.w;
    *(bf16x8*)(clsb + i) = o;
  }
}

// ---------------------------------------------------------------------------
// w2 (unchanged): per k one MFMA GEMM, A direct from global.
// ---------------------------------------------------------------------------
__global__ __launch_bounds__(256) void w2_kernel(const float* __restrict__ conv_w,
                                                 const bf16_t* __restrict__ clsb,
                                                 bf16_t* __restrict__ Vt) {
  const int k = blockIdx.y;
  const int m0 = blockIdx.x * 128;
  const int tid = threadIdx.x;
  const int w = tid >> 6, lane = tid & 63;
  const int wm = w & 1, wn = w >> 1;
  const int lrow = lane & 15, quad = lane >> 4;
  const float* A = conv_w + (size_t)k * 2097152;
  f32x4 acc[4][2] = {};
#pragma unroll 2
  for (int kk = 0; kk < 16; kk++) {
    const int d0 = kk * 32 + quad * 8;
    const bf16x8 b0 = *(const bf16x8*)(clsb + (wn * 32 + lrow) * 512 + kk * 32 + quad * 8);
    const bf16x8 b1 = *(const bf16x8*)(clsb + (wn * 32 + 16 + lrow) * 512 + kk * 32 + quad * 8);
#pragma unroll
    for (int mi = 0; mi < 4; mi++) {
      const int ih = m0 + wm * 64 + mi * 16 + lrow;
      const float* ap = A + (size_t)d0 * 4096 + ih;
      bf16x8 a;
      a[0] = (bf16_t)ap[0 * 4096]; a[1] = (bf16_t)ap[1 * 4096];
      a[2] = (bf16_t)ap[2 * 4096]; a[3] = (bf16_t)ap[3 * 4096];
      a[4] = (bf16_t)ap[4 * 4096]; a[5] = (bf16_t)ap[5 * 4096];
      a[6] = (bf16_t)ap[6 * 4096]; a[7] = (bf16_t)ap[7 * 4096];
      acc[mi][0] = __builtin_amdgcn_mfma_f32_16x16x32_bf16(a, b0, acc[mi][0], 0, 0, 0);
      acc[mi][1] = __builtin_amdgcn_mfma_f32_16x16x32_bf16(a, b1, acc[mi][1], 0, 0, 0);
    }
  }
#pragma unroll
  for (int mi = 0; mi < 4; mi++) {
#pragma unroll
    for (int dd = 0; dd < 4; dd++) {
      const int ih = m0 + wm * 64 + mi * 16 + quad * 4 + dd;
      const int i = ih >> 3, h = ih & 7;
      const int o = k - h;
      if (o >= 0) {
#pragma unroll
        for (int ni = 0; ni < 2; ni++) {
          const int l = wn * 32 + ni * 16 + lrow;
          Vt[(size_t)(k * 64 + l) * 4096 + o * 512 + i] = (bf16_t)acc[mi][ni][dd];
        }
      }
    }
  }
}

// ---------------------------------------------------------------------------
// bias2 (unchanged)
// ---------------------------------------------------------------------------
__global__ __launch_bounds__(256) void bias2_kernel(const float* __restrict__ conv_b,
                                                    const float* __restrict__ cls_w,
                                                    const float* __restrict__ cls_b,
                                                    float* __restrict__ bias2) {
  const int k = blockIdx.x;
  const int tid = threadIdx.x;
  const int l = tid & 63, c = tid >> 6;
  __shared__ float partb[4][64];
  float s = 0.f;
  for (int d = c * 128; d < c * 128 + 128; d++)
    s += conv_b[k * D_ + d] * cls_w[l * D_ + d];
  partb[c][l] = s;
  __syncthreads();
  if (tid < 64)
    bias2[k * 64 + tid] = cls_b[tid] + partb[0][tid] + partb[1][tid] + partb[2][tid] + partb[3][tid];
}

// ---------------------------------------------------------------------------
// ls v3: NO LDS, NO barriers. A and B fragments both direct from global
// (Vt is L2-resident, 4 MB; lanes {r,r+16,r+32,r+48} form 64B lines).
// Packed-dword epilogue (unchanged semantics).
// ---------------------------------------------------------------------------
__global__ __launch_bounds__(256) void ls_mfma(const bf16_t* __restrict__ Awr,
                                               const bf16_t* __restrict__ Vt,
                                               const float* __restrict__ bias2,
                                               const int* __restrict__ mask,
                                               unsigned int* __restrict__ ELSd) {
  const int tid = threadIdx.x;
  const int m0 = blockIdx.x * 64;
  const int p = blockIdx.y;
  const int w = tid >> 6, lane = tid & 63;
  const int wm = w & 1, wn = w >> 1;
  const int lrow = lane & 15, quad = lane >> 4;
  unsigned int s0bits[2][2][4];

#define MFMA_BF16(A, Bv, C) __builtin_amdgcn_mfma_f32_16x16x32_bf16((A), (Bv), (C), 0, 0, 0)

  for (int s = 0; s < 2; s++) {
    const int kS = (s == 0) ? (7 - p) : p;
    const int NC = (kS + 1) * 4;
    f32x4 acc00 = {}, acc01 = {}, acc10 = {}, acc11 = {};
    const bf16_t* vb0 = Vt + (size_t)(kS * 64 + wn * 32 + lrow) * 4096 + quad * 8;
    const bf16_t* vb1 = Vt + (size_t)(kS * 64 + wn * 32 + 16 + lrow) * 4096 + quad * 8;
    for (int c = 0; c < NC; c++) {
      const int o = c >> 2, jj = (c & 3) * 128;
      int r0 = m0 + wm * 32 + lrow - o;       if (r0 < 0) r0 = 0;
      int r1 = m0 + wm * 32 + 16 + lrow - o;  if (r1 < 0) r1 = 0;
      const bf16_t* a0p = Awr + (size_t)r0 * 512 + jj + quad * 8;
      const bf16_t* a1p = Awr + (size_t)r1 * 512 + jj + quad * 8;
      const bf16_t* b0p = vb0 + o * 512 + jj;
      const bf16_t* b1p = vb1 + o * 512 + jj;
#pragma unroll
      for (int kst = 0; kst < 4; kst++) {
        const bf16x8 a0 = *(const bf16x8*)(a0p + kst * 32);
        const bf16x8 a1 = *(const bf16x8*)(a1p + kst * 32);
        const bf16x8 b0 = *(const bf16x8*)(b0p + kst * 32);
        const bf16x8 b1 = *(const bf16x8*)(b1p + kst * 32);
        acc00 = MFMA_BF16(a0, b0, acc00);
        acc01 = MFMA_BF16(a0, b1, acc01);
        acc10 = MFMA_BF16(a1, b0, acc10);
        acc11 = MFMA_BF16(a1, b1, acc11);
      }
    }
    const int lc0 = wn * 32 + lrow, lc1 = wn * 32 + 16 + lrow;
    const float bn0 = bias2[kS * 64 + lc0];
    const float bn1 = bias2[kS * 64 + lc1];
#pragma unroll
    for (int mi = 0; mi < 2; mi++) {
      const f32x4 va = (mi == 0) ? acc00 : acc10;
      const f32x4 vbb = (mi == 0) ? acc01 : acc11;
#pragma unroll
      for (int d = 0; d < 4; d++) {
        const int m = m0 + wm * 32 + mi * 16 + quad * 4 + d;
        const int t = m & 255;
        const bool mok = (mask[m] == 1) && (t >= kS);
        const float e0 = (!mok || lc0 == 0) ? 0.f : __expf(va[d] + bn0);
        const float e1 = (!mok || lc1 == 0) ? 0.f : __expf(vbb[d] + bn1);
        if (s == 0) {
          s0bits[mi][0][d] = f2bfbits(e0);
          s0bits[mi][1][d] = f2bfbits(e1);
        } else {
          const unsigned int dw0 = s0bits[mi][0][d] | (f2bfbits(e0) << 16);
          const unsigned int dw1 = s0bits[mi][1][d] | (f2bfbits(e1) << 16);
          ELSd[((size_t)p * 8192 + m) * 64 + lc0] = dw0;
          ELSd[((size_t)p * 8192 + m) * 64 + lc1] = dw1;
        }
      }
    }
  }
#undef MFMA_BF16
}

// ---------------------------------------------------------------------------
// dp v3 (unchanged from R10)
// ---------------------------------------------------------------------------
__global__ __launch_bounds__(256, 1) void dp_kernel(const float* __restrict__ T,
                                                    const float* __restrict__ Tfb_g,
                                                    const unsigned int* __restrict__ ELSd,
                                                    float* __restrict__ Mg_lin,
                                                    float* __restrict__ cs_g) {
  const int b = blockIdx.x, tid = threadIdx.x;
  const int w = tid >> 6, l = tid & 63;
  __shared__ __align__(16) float ebuf[64];
  __shared__ float part[4][72];
  __shared__ __align__(16) float pmax[4];
  f32x4 rTq[4];
#pragma unroll
  for (int q = 0; q < 4; q++) {
#pragma unroll
    for (int e = 0; e < 4; e++) rTq[q][e] = __expf(T[l * 64 + w * 16 + q * 4 + e]);
  }
  float mh0 = 0.f, mh1 = 0.f, mh2 = 0.f, mh3 = 0.f, mh4 = 0.f, mh5 = 0.f, mh6 = 0.f, mh7 = 0.f;
  float c = 0.f;
  const unsigned int* e0p = ELSd + ((size_t)0 * 8192 + b * 256) * 64 + l;
  const unsigned int* e1p = ELSd + ((size_t)1 * 8192 + b * 256) * 64 + l;
  const unsigned int* e2p = ELSd + ((size_t)2 * 8192 + b * 256) * 64 + l;
  const unsigned int* e3p = ELSd + ((size_t)3 * 8192 + b * 256) * 64 + l;
  uint4 r0, r1, r2, r3;
  if (w == 0) {
    mh0 = __expf(Tfb_g[l]);
    r0 = make_uint4(e0p[0 * 64], e1p[0 * 64], e2p[0 * 64], e3p[0 * 64]);
    r1 = make_uint4(e0p[1 * 64], e1p[1 * 64], e2p[1 * 64], e3p[1 * 64]);
    r2 = make_uint4(e0p[2 * 64], e1p[2 * 64], e2p[2 * 64], e3p[2 * 64]);
    r3 = make_uint4(e0p[3 * 64], e1p[3 * 64], e2p[3 * 64], e3p[3 * 64]);
  }
  for (int t4 = 0; t4 < 256; t4 += 4) {
#pragma unroll
    for (int u = 0; u < 4; u++) {
      const int t = t4 + u;
      if (w == 0) {
        if (t > 0) {
          const float p0 = part[0][l], p1 = part[1][l], p2 = part[2][l], p3 = part[3][l];
          const float m4 = (p0 + p1) + (p2 + p3);
          if ((t & 3) == 0) {
            const f32x4 pm = *(const f32x4*)pmax;
            float S = fmaxf(fmaxf(pm[0], pm[1]), fmaxf(pm[2], pm[3]));
            S = fmaxf(S, 1e-30f);
            const float inv = __builtin_amdgcn_rcpf(S);
            c += __logf(S);
            mh7 = mh6 * inv; mh6 = mh5 * inv; mh5 = mh4 * inv; mh4 = mh3 * inv;
            mh3 = mh2 * inv; mh2 = mh1 * inv; mh1 = mh0 * inv; mh0 = m4 * inv;
          } else {
            mh7 = mh6; mh6 = mh5; mh5 = mh4; mh4 = mh3;
            mh3 = mh2; mh2 = mh1; mh1 = mh0; mh0 = m4;
          }
        }
        const uint4 q = (u == 0) ? r0 : (u == 1) ? r1 : (u == 2) ? r2 : r3;
        const float f7 = u2f(q.x << 16), fk0 = u2f(q.x & 0xFFFF0000u);
        const float f6 = u2f(q.y << 16), fk1 = u2f(q.y & 0xFFFF0000u);
        const float f5 = u2f(q.z << 16), fk2 = u2f(q.z & 0xFFFF0000u);
        const float f4 = u2f(q.w << 16), fk3 = u2f(q.w & 0xFFFF0000u);
        const float e = ((fk0 * mh0 + fk1 * mh1) + (fk2 * mh2 + fk3 * mh3)) +
                        ((f4 * mh4 + f5 * mh5) + (f6 * mh6 + f7 * mh7));
        ebuf[l] = e;
        int nt = t + 4; if (nt > 255) nt = 255;
        const uint4 nv = make_uint4(e0p[(size_t)nt * 64], e1p[(size_t)nt * 64],
                                    e2p[(size_t)nt * 64], e3p[(size_t)nt * 64]);
        if (u == 0) r0 = nv; else if (u == 1) r1 = nv; else if (u == 2) r2 = nv; else r3 = nv;
      } else if (w == 1) {
        if (t > 0) {
          const float p0 = part[0][l], p1 = part[1][l], p2 = part[2][l], p3 = part[3][l];
          const float m4 = (p0 + p1) + (p2 + p3);
          Mg_lin[((size_t)b * 256 + (t - 1)) * 64 + l] = m4;
          if (l == 0) cs_g[b * 256 + (t - 1)] = c;
          if ((t & 3) == 0) {
            const f32x4 pm = *(const f32x4*)pmax;
            float S = fmaxf(fmaxf(pm[0], pm[1]), fmaxf(pm[2], pm[3]));
            S = fmaxf(S, 1e-30f);
            c += __logf(S);
          }
        }
      }
      __syncthreads();
      {
        const f32x4* evp = (const f32x4*)ebuf;
        const f32x4 v0 = evp[w * 4 + 0], v1 = evp[w * 4 + 1];
        const f32x4 v2 = evp[w * 4 + 2], v3 = evp[w * 4 + 3];
        f32x4 s01 = rTq[0] * v0 + rTq[1] * v1;
        f32x4 s23 = rTq[2] * v2 + rTq[3] * v3;
        const f32x4 sv = s01 + s23;
        part[w][l] = (sv[0] + sv[1]) + (sv[2] + sv[3]);
        const f32x4 mx = __builtin_elementwise_max(__builtin_elementwise_max(v0, v1),
                                                   __builtin_elementwise_max(v2, v3));
        if (l == 0) pmax[w] = fmaxf(fmaxf(mx[0], mx[1]), fmaxf(mx[2], mx[3]));
      }
      __syncthreads();
    }
  }
  if (w == 1) {
    const float p0 = part[0][l], p1 = part[1][l], p2 = part[2][l], p3 = part[3][l];
    const float m4 = (p0 + p1) + (p2 + p3);
    Mg_lin[((size_t)b * 256 + 255) * 64 + l] = m4;
    if (l == 0) cs_g[b * 256 + 255] = c;
  }
}

// ---------------------------------------------------------------------------
// Final gather (unchanged from R10)
// ---------------------------------------------------------------------------
__global__ __launch_bounds__(64) void final_kernel(const int* __restrict__ mask,
                                                   const float* __restrict__ Tfb_g,
                                                   const float* __restrict__ T2e_g,
                                                   const unsigned int* __restrict__ ELSd,
                                                   const float* __restrict__ Mg_lin,
                                                   const float* __restrict__ cs_g,
                                                   float* __restrict__ out) {
  const int b = blockIdx.x, lane = threadIdx.x;
  int lenp = 0;
  for (int s = lane; s < S_; s += 64) lenp += (mask[b * S_ + s] == 1) ? 1 : 0;
#pragma unroll
  for (int off = 32; off > 0; off >>= 1) lenp += __shfl_xor(lenp, off);
  const int len = lenp;
  const float t2e = T2e_g[lane];
  float vals[8];
  float mx = -3.4e38f;
#pragma unroll
  for (int k = 0; k < 8; k++) {
    int tk = len - 1 - k;
    if (tk < 0) tk = S_ - 1;
    float g;
    if (k > tk) {
      g = NEGV;
    } else {
      const int p = (k < 4) ? k : (7 - k);
      const unsigned int dw = ELSd[((size_t)p * 8192 + b * 256 + tk) * 64 + lane];
      const float elsv = (k < 4) ? u2f(dw & 0xFFFF0000u) : u2f(dw << 16);
      const float ls = (elsv > 0.f) ? __logf(elsv) : NEGV;
      if (k == tk) {
        g = ls + Tfb_g[lane];
      } else if (mask[b * S_ + tk] == 1) {
        const int u = tk - 1 - k;
        const float mlin = Mg_lin[((size_t)b * S_ + u) * 64 + lane];
        const float M = (mlin > 0.f) ? (__logf(mlin) + cs_g[b * S_ + u]) : -1e30f;
        g = ls + M;
      } else {
        g = NEGV;
      }
    }
    const float v = g + t2e;
    vals[k] = v;
    mx = fmaxf(mx, v);
  }
#pragma unroll
  for (int off = 32; off > 0; off >>= 1) mx = fmaxf(mx, __shfl_xor(mx, off));
  float s = 0.f;
#pragma unroll
  for (int k = 0; k < 8; k++) s += __expf(vals[k] - mx);
#pragma unroll
  for (int off = 32; off > 0; off >>= 1) s += __shfl_xor(s, off);
  if (lane == 0) out[b] = __logf(s) + mx;
}

// ---------------------------------------------------------------------------
extern "C" void kernel_launch(void* const* d_in, const int* in_sizes, int n_in,
                              void* d_out, int out_size, void* d_ws, size_t ws_size,
                              hipStream_t stream) {
  const float* wr     = (const float*)d_in[0];
  const int*   mask   = (const int*)d_in[1];
  const float* conv_w = (const float*)d_in[2];
  const float* conv_b = (const float*)d_in[3];
  const float* cls_w  = (const float*)d_in[4];
  const float* cls_b  = (const float*)d_in[5];
  const float* T      = (const float*)d_in[6];
  const float* Tfb    = (const float*)d_in[7];
  const float* T2e    = (const float*)d_in[8];
  float* out = (float*)d_out;

  float* ws = (float*)d_ws;
  bf16_t* Vt    = (bf16_t*)ws;                      // [512][4096] bf16 (4 MB)
  bf16_t* Awr   = (bf16_t*)(ws + 1048576);          // [8192][512] bf16 (8 MB)
  float*  bias2 = ws + 3145728;                     // [8][64]
  unsigned int* ELSd = (unsigned int*)(ws + 3146240);  // [4][8192][64] dwords (8 MB)
  float*  Mg    = ws + 5243392;                     // [32][256][64] (2 MB)
  float*  cs    = ws + 5767680;                     // [32][256]
  bf16_t* clsb  = (bf16_t*)(ws + 5775872);          // [64][512] bf16

  cast_kernel<<<2064, 256, 0, stream>>>(wr, Awr, cls_w, clsb);
  w2_kernel<<<dim3(32, 8), 256, 0, stream>>>(conv_w, clsb, Vt);
  bias2_kernel<<<8, 256, 0, stream>>>(conv_b, cls_w, cls_b, bias2);
  ls_mfma<<<dim3(128, 4), 256, 0, stream>>>(Awr, Vt, bias2, mask, ELSd);
  dp_kernel<<<32, 256, 0, stream>>>(T, Tfb, ELSd, Mg, cs);
  final_kernel<<<32, 64, 0, stream>>>(mask, Tfb, T2e, ELSd, Mg, cs, out);
}

// Round 13
// 304.427 us; speedup vs baseline: 1.2090x; 1.2090x over previous
//
#include <hip/hip_runtime.h>
#include <hip/hip_bf16.h>

#define NEGV (-10000.0f)
constexpr int B_ = 32, S_ = 256, D_ = 512, K_ = 8, L_ = 64;

typedef __bf16 bf16_t;
typedef bf16_t bf16x8 __attribute__((ext_vector_type(8)));
typedef float f32x4 __attribute__((ext_vector_type(4)));

__device__ __forceinline__ float u2f(unsigned int u) {
  union { unsigned int u; float f; } x; x.u = u; return x.f;
}
__device__ __forceinline__ unsigned int f2bfbits(float f) {
  union { bf16_t h; unsigned short u; } x; x.h = (bf16_t)f; return (unsigned int)x.u;
}

// ---------------------------------------------------------------------------
// cast word_rep -> bf16 Awr [8192][512]; blocks >= 2048 cast cls_w -> bf16.
// ---------------------------------------------------------------------------
__global__ __launch_bounds__(256) void cast_kernel(const float* __restrict__ wr,
                                                   bf16_t* __restrict__ Awr,
                                                   const float* __restrict__ cls_w,
                                                   bf16_t* __restrict__ clsb) {
  const int bid = blockIdx.x;
  if (bid < 2048) {
    const int i = (bid * 256 + threadIdx.x) * 8;
    const float4 a = *(const float4*)(wr + i);
    const float4 b = *(const float4*)(wr + i + 4);
    bf16x8 o;
    o[0] = (bf16_t)a.x; o[1] = (bf16_t)a.y; o[2] = (bf16_t)a.z; o[3] = (bf16_t)a.w;
    o[4] = (bf16_t)b.x; o[5] = (bf16_t)b.y; o[6] = (bf16_t)b.z; o[7] = (bf16_t)b.w;
    *(bf16x8*)(Awr + i) = o;
  } else {
    const int i = ((bid - 2048) * 256 + threadIdx.x) * 8;
    const float4 a = *(const float4*)(cls_w + i);
    const float4 b = *(const float4*)(cls_w + i + 4);
    bf16x8 o;
    o[0] = (bf16_t)a.x; o[1] = (bf16_t)a.y; o[2] = (bf16_t)a.z; o[3] = (bf16_t)a.w;
    o[4] = (bf16_t)b.x; o[5] = (bf16_t)b.y; o[6] = (bf16_t)b.z; o[7] = (bf16_t)b.w;
    *(bf16x8*)(clsb + i) = o;
  }
}

// ---------------------------------------------------------------------------
// w2 (unchanged): per k one MFMA GEMM, A direct from global.
// ---------------------------------------------------------------------------
__global__ __launch_bounds__(256) void w2_kernel(const float* __restrict__ conv_w,
                                                 const bf16_t* __restrict__ clsb,
                                                 bf16_t* __restrict__ Vt) {
  const int k = blockIdx.y;
  const int m0 = blockIdx.x * 128;
  const int tid = threadIdx.x;
  const int w = tid >> 6, lane = tid & 63;
  const int wm = w & 1, wn = w >> 1;
  const int lrow = lane & 15, quad = lane >> 4;
  const float* A = conv_w + (size_t)k * 2097152;
  f32x4 acc[4][2] = {};
#pragma unroll 2
  for (int kk = 0; kk < 16; kk++) {
    const int d0 = kk * 32 + quad * 8;
    const bf16x8 b0 = *(const bf16x8*)(clsb + (wn * 32 + lrow) * 512 + kk * 32 + quad * 8);
    const bf16x8 b1 = *(const bf16x8*)(clsb + (wn * 32 + 16 + lrow) * 512 + kk * 32 + quad * 8);
#pragma unroll
    for (int mi = 0; mi < 4; mi++) {
      const int ih = m0 + wm * 64 + mi * 16 + lrow;
      const float* ap = A + (size_t)d0 * 4096 + ih;
      bf16x8 a;
      a[0] = (bf16_t)ap[0 * 4096]; a[1] = (bf16_t)ap[1 * 4096];
      a[2] = (bf16_t)ap[2 * 4096]; a[3] = (bf16_t)ap[3 * 4096];
      a[4] = (bf16_t)ap[4 * 4096]; a[5] = (bf16_t)ap[5 * 4096];
      a[6] = (bf16_t)ap[6 * 4096]; a[7] = (bf16_t)ap[7 * 4096];
      acc[mi][0] = __builtin_amdgcn_mfma_f32_16x16x32_bf16(a, b0, acc[mi][0], 0, 0, 0);
      acc[mi][1] = __builtin_amdgcn_mfma_f32_16x16x32_bf16(a, b1, acc[mi][1], 0, 0, 0);
    }
  }
#pragma unroll
  for (int mi = 0; mi < 4; mi++) {
#pragma unroll
    for (int dd = 0; dd < 4; dd++) {
      const int ih = m0 + wm * 64 + mi * 16 + quad * 4 + dd;
      const int i = ih >> 3, h = ih & 7;
      const int o = k - h;
      if (o >= 0) {
#pragma unroll
        for (int ni = 0; ni < 2; ni++) {
          const int l = wn * 32 + ni * 16 + lrow;
          Vt[(size_t)(k * 64 + l) * 4096 + o * 512 + i] = (bf16_t)acc[mi][ni][dd];
        }
      }
    }
  }
}

// ---------------------------------------------------------------------------
// bias2 (unchanged)
// ---------------------------------------------------------------------------
__global__ __launch_bounds__(256) void bias2_kernel(const float* __restrict__ conv_b,
                                                    const float* __restrict__ cls_w,
                                                    const float* __restrict__ cls_b,
                                                    float* __restrict__ bias2) {
  const int k = blockIdx.x;
  const int tid = threadIdx.x;
  const int l = tid & 63, c = tid >> 6;
  __shared__ float partb[4][64];
  float s = 0.f;
  for (int d = c * 128; d < c * 128 + 128; d++)
    s += conv_b[k * D_ + d] * cls_w[l * D_ + d];
  partb[c][l] = s;
  __syncthreads();
  if (tid < 64)
    bias2[k * 64 + tid] = cls_b[tid] + partb[0][tid] + partb[1][tid] + partb[2][tid] + partb[3][tid];
}

// ---------------------------------------------------------------------------
// ls v4 (fixed): A-window resident in LDS (71 rows x 512, stride 520),
// staged ONCE. One wave per strip ({7,0,5,2}/{6,1,4,3}), barrier-free K-loop,
// A-frags from LDS (address = row*LDA + col, NO o*512 term), B direct from
// L2-resident Vt. Cross-wave packed-dword epilogue. grid (128, 2).
// ---------------------------------------------------------------------------
__global__ __launch_bounds__(256) void ls_mfma(const bf16_t* __restrict__ Awr,
                                               const bf16_t* __restrict__ Vt,
                                               const float* __restrict__ bias2,
                                               const int* __restrict__ mask,
                                               unsigned int* __restrict__ ELSd) {
  constexpr int LDA = 520;
  __shared__ __align__(16) bf16_t As[71 * LDA];  // 73.8 KB
  const int tid = threadIdx.x;
  const int m0 = blockIdx.x * 64;
  const int y = blockIdx.y;
  const int w = tid >> 6, lane = tid & 63;
  const int lrow = lane & 15, quad = lane >> 4;
  const int tblA[4] = {7, 0, 5, 2}, tblB[4] = {6, 1, 4, 3};
  const int kS = (y == 0) ? tblA[w] : tblB[w];

  // stage A rows m0-7 .. m0+63 (71 rows x 512) once
  for (int c = tid; c < 71 * 64; c += 256) {
    const int row = c >> 6, col8 = c & 63;
    int src = m0 - 7 + row;
    if (src < 0) src = 0;
    const uint4 v = *(const uint4*)(Awr + (size_t)src * 512 + col8 * 8);
    *(uint4*)(&As[row * LDA + col8 * 8]) = v;
  }
  __syncthreads();

  f32x4 acc[4][4] = {};  // [mi][ni] : 64m x 64l
  const int NJ = 16 * (kS + 1);
  const bf16_t* vbase = Vt + (size_t)(kS * 64 + lrow) * 4096 + quad * 8;
#pragma unroll 2
  for (int j = 0; j < NJ; j++) {
    const int o = j >> 4;
    const int col = (j & 15) * 32;
    bf16x8 bfr[4];
#pragma unroll
    for (int ni = 0; ni < 4; ni++)
      bfr[ni] = *(const bf16x8*)(vbase + (size_t)(ni * 16) * 4096 + j * 32);
    const int abase = (lrow + 7 - o) * LDA + col + quad * 8;  // FIXED: no o*512
#pragma unroll
    for (int mi = 0; mi < 4; mi++) {
      const bf16x8 a = *(const bf16x8*)(&As[abase + mi * 16 * LDA]);
#pragma unroll
      for (int ni = 0; ni < 4; ni++)
        acc[mi][ni] = __builtin_amdgcn_mfma_f32_16x16x32_bf16(a, bfr[ni], acc[mi][ni], 0, 0, 0);
    }
  }

  // epilogue: bias + exp + bf16, park in LDS, then packed-dword coalesced store
  __syncthreads();  // all A reads done; reuse As as buf[4][64][64] u16 (32 KB)
  unsigned short* buf = (unsigned short*)As;
#pragma unroll
  for (int ni = 0; ni < 4; ni++) {
    const int l = ni * 16 + lrow;
    const float bn = bias2[kS * 64 + l];
#pragma unroll
    for (int mi = 0; mi < 4; mi++) {
#pragma unroll
      for (int d = 0; d < 4; d++) {
        const int ml = mi * 16 + quad * 4 + d;
        const int m = m0 + ml;
        const int t = m & 255;
        const bool mok = (mask[m] == 1) && (t >= kS) && (l != 0);
        const float e = mok ? __expf(acc[mi][ni][d] + bn) : 0.f;
        buf[w * 4096 + ml * 64 + l] = (unsigned short)f2bfbits(e);
      }
    }
  }
  __syncthreads();
  // planes: (w0,w1) -> plane y (lo=k(7-y) from w0, hi=k(y) from w1);
  //         (w2,w3) -> plane 2+y.
#pragma unroll
  for (int g = 0; g < 2; g++) {
    const int plane = g * 2 + y;
    const unsigned short* lo = buf + (g * 2) * 4096;
    const unsigned short* hi = buf + (g * 2 + 1) * 4096;
#pragma unroll
    for (int it = 0; it < 16; it++) {
      const int idx = it * 256 + tid;
      const unsigned int dw = (unsigned int)lo[idx] | ((unsigned int)hi[idx] << 16);
      ELSd[((size_t)plane * 8192 + m0 + (idx >> 6)) * 64 + (idx & 63)] = dw;
    }
  }
}

// ---------------------------------------------------------------------------
// dp v3 (unchanged from R10)
// ---------------------------------------------------------------------------
__global__ __launch_bounds__(256, 1) void dp_kernel(const float* __restrict__ T,
                                                    const float* __restrict__ Tfb_g,
                                                    const unsigned int* __restrict__ ELSd,
                                                    float* __restrict__ Mg_lin,
                                                    float* __restrict__ cs_g) {
  const int b = blockIdx.x, tid = threadIdx.x;
  const int w = tid >> 6, l = tid & 63;
  __shared__ __align__(16) float ebuf[64];
  __shared__ float part[4][72];
  __shared__ __align__(16) float pmax[4];
  f32x4 rTq[4];
#pragma unroll
  for (int q = 0; q < 4; q++) {
#pragma unroll
    for (int e = 0; e < 4; e++) rTq[q][e] = __expf(T[l * 64 + w * 16 + q * 4 + e]);
  }
  float mh0 = 0.f, mh1 = 0.f, mh2 = 0.f, mh3 = 0.f, mh4 = 0.f, mh5 = 0.f, mh6 = 0.f, mh7 = 0.f;
  float c = 0.f;
  const unsigned int* e0p = ELSd + ((size_t)0 * 8192 + b * 256) * 64 + l;
  const unsigned int* e1p = ELSd + ((size_t)1 * 8192 + b * 256) * 64 + l;
  const unsigned int* e2p = ELSd + ((size_t)2 * 8192 + b * 256) * 64 + l;
  const unsigned int* e3p = ELSd + ((size_t)3 * 8192 + b * 256) * 64 + l;
  uint4 r0, r1, r2, r3;
  if (w == 0) {
    mh0 = __expf(Tfb_g[l]);
    r0 = make_uint4(e0p[0 * 64], e1p[0 * 64], e2p[0 * 64], e3p[0 * 64]);
    r1 = make_uint4(e0p[1 * 64], e1p[1 * 64], e2p[1 * 64], e3p[1 * 64]);
    r2 = make_uint4(e0p[2 * 64], e1p[2 * 64], e2p[2 * 64], e3p[2 * 64]);
    r3 = make_uint4(e0p[3 * 64], e1p[3 * 64], e2p[3 * 64], e3p[3 * 64]);
  }
  for (int t4 = 0; t4 < 256; t4 += 4) {
#pragma unroll
    for (int u = 0; u < 4; u++) {
      const int t = t4 + u;
      if (w == 0) {
        if (t > 0) {
          const float p0 = part[0][l], p1 = part[1][l], p2 = part[2][l], p3 = part[3][l];
          const float m4 = (p0 + p1) + (p2 + p3);
          if ((t & 3) == 0) {
            const f32x4 pm = *(const f32x4*)pmax;
            float S = fmaxf(fmaxf(pm[0], pm[1]), fmaxf(pm[2], pm[3]));
            S = fmaxf(S, 1e-30f);
            const float inv = __builtin_amdgcn_rcpf(S);
            c += __logf(S);
            mh7 = mh6 * inv; mh6 = mh5 * inv; mh5 = mh4 * inv; mh4 = mh3 * inv;
            mh3 = mh2 * inv; mh2 = mh1 * inv; mh1 = mh0 * inv; mh0 = m4 * inv;
          } else {
            mh7 = mh6; mh6 = mh5; mh5 = mh4; mh4 = mh3;
            mh3 = mh2; mh2 = mh1; mh1 = mh0; mh0 = m4;
          }
        }
        const uint4 q = (u == 0) ? r0 : (u == 1) ? r1 : (u == 2) ? r2 : r3;
        const float f7 = u2f(q.x << 16), fk0 = u2f(q.x & 0xFFFF0000u);
        const float f6 = u2f(q.y << 16), fk1 = u2f(q.y & 0xFFFF0000u);
        const float f5 = u2f(q.z << 16), fk2 = u2f(q.z & 0xFFFF0000u);
        const float f4 = u2f(q.w << 16), fk3 = u2f(q.w & 0xFFFF0000u);
        const float e = ((fk0 * mh0 + fk1 * mh1) + (fk2 * mh2 + fk3 * mh3)) +
                        ((f4 * mh4 + f5 * mh5) + (f6 * mh6 + f7 * mh7));
        ebuf[l] = e;
        int nt = t + 4; if (nt > 255) nt = 255;
        const uint4 nv = make_uint4(e0p[(size_t)nt * 64], e1p[(size_t)nt * 64],
                                    e2p[(size_t)nt * 64], e3p[(size_t)nt * 64]);
        if (u == 0) r0 = nv; else if (u == 1) r1 = nv; else if (u == 2) r2 = nv; else r3 = nv;
      } else if (w == 1) {
        if (t > 0) {
          const float p0 = part[0][l], p1 = part[1][l], p2 = part[2][l], p3 = part[3][l];
          const float m4 = (p0 + p1) + (p2 + p3);
          Mg_lin[((size_t)b * 256 + (t - 1)) * 64 + l] = m4;
          if (l == 0) cs_g[b * 256 + (t - 1)] = c;
          if ((t & 3) == 0) {
            const f32x4 pm = *(const f32x4*)pmax;
            float S = fmaxf(fmaxf(pm[0], pm[1]), fmaxf(pm[2], pm[3]));
            S = fmaxf(S, 1e-30f);
            c += __logf(S);
          }
        }
      }
      __syncthreads();
      {
        const f32x4* evp = (const f32x4*)ebuf;
        const f32x4 v0 = evp[w * 4 + 0], v1 = evp[w * 4 + 1];
        const f32x4 v2 = evp[w * 4 + 2], v3 = evp[w * 4 + 3];
        f32x4 s01 = rTq[0] * v0 + rTq[1] * v1;
        f32x4 s23 = rTq[2] * v2 + rTq[3] * v3;
        const f32x4 sv = s01 + s23;
        part[w][l] = (sv[0] + sv[1]) + (sv[2] + sv[3]);
        const f32x4 mx = __builtin_elementwise_max(__builtin_elementwise_max(v0, v1),
                                                   __builtin_elementwise_max(v2, v3));
        if (l == 0) pmax[w] = fmaxf(fmaxf(mx[0], mx[1]), fmaxf(mx[2], mx[3]));
      }
      __syncthreads();
    }
  }
  if (w == 1) {
    const float p0 = part[0][l], p1 = part[1][l], p2 = part[2][l], p3 = part[3][l];
    const float m4 = (p0 + p1) + (p2 + p3);
    Mg_lin[((size_t)b * 256 + 255) * 64 + l] = m4;
    if (l == 0) cs_g[b * 256 + 255] = c;
  }
}

// ---------------------------------------------------------------------------
// Final gather (unchanged from R10)
// ---------------------------------------------------------------------------
__global__ __launch_bounds__(64) void final_kernel(const int* __restrict__ mask,
                                                   const float* __restrict__ Tfb_g,
                                                   const float* __restrict__ T2e_g,
                                                   const unsigned int* __restrict__ ELSd,
                                                   const float* __restrict__ Mg_lin,
                                                   const float* __restrict__ cs_g,
                                                   float* __restrict__ out) {
  const int b = blockIdx.x, lane = threadIdx.x;
  int lenp = 0;
  for (int s = lane; s < S_; s += 64) lenp += (mask[b * S_ + s] == 1) ? 1 : 0;
#pragma unroll
  for (int off = 32; off > 0; off >>= 1) lenp += __shfl_xor(lenp, off);
  const int len = lenp;
  const float t2e = T2e_g[lane];
  float vals[8];
  float mx = -3.4e38f;
#pragma unroll
  for (int k = 0; k < 8; k++) {
    int tk = len - 1 - k;
    if (tk < 0) tk = S_ - 1;
    float g;
    if (k > tk) {
      g = NEGV;
    } else {
      const int p = (k < 4) ? k : (7 - k);
      const unsigned int dw = ELSd[((size_t)p * 8192 + b * 256 + tk) * 64 + lane];
      const float elsv = (k < 4) ? u2f(dw & 0xFFFF0000u) : u2f(dw << 16);
      const float ls = (elsv > 0.f) ? __logf(elsv) : NEGV;
      if (k == tk) {
        g = ls + Tfb_g[lane];
      } else if (mask[b * S_ + tk] == 1) {
        const int u = tk - 1 - k;
        const float mlin = Mg_lin[((size_t)b * S_ + u) * 64 + lane];
        const float M = (mlin > 0.f) ? (__logf(mlin) + cs_g[b * S_ + u]) : -1e30f;
        g = ls + M;
      } else {
        g = NEGV;
      }
    }
    const float v = g + t2e;
    vals[k] = v;
    mx = fmaxf(mx, v);
  }
#pragma unroll
  for (int off = 32; off > 0; off >>= 1) mx = fmaxf(mx, __shfl_xor(mx, off));
  float s = 0.f;
#pragma unroll
  for (int k = 0; k < 8; k++) s += __expf(vals[k] - mx);
#pragma unroll
  for (int off = 32; off > 0; off >>= 1) s += __shfl_xor(s, off);
  if (lane == 0) out[b] = __logf(s) + mx;
}

// ---------------------------------------------------------------------------
extern "C" void kernel_launch(void* const* d_in, const int* in_sizes, int n_in,
                              void* d_out, int out_size, void* d_ws, size_t ws_size,
                              hipStream_t stream) {
  const float* wr     = (const float*)d_in[0];
  const int*   mask   = (const int*)d_in[1];
  const float* conv_w = (const float*)d_in[2];
  const float* conv_b = (const float*)d_in[3];
  const float* cls_w  = (const float*)d_in[4];
  const float* cls_b  = (const float*)d_in[5];
  const float* T      = (const float*)d_in[6];
  const float* Tfb    = (const float*)d_in[7];
  const float* T2e    = (const float*)d_in[8];
  float* out = (float*)d_out;

  float* ws = (float*)d_ws;
  bf16_t* Vt    = (bf16_t*)ws;                      // [512][4096] bf16 (4 MB)
  bf16_t* Awr   = (bf16_t*)(ws + 1048576);          // [8192][512] bf16 (8 MB)
  float*  bias2 = ws + 3145728;                     // [8][64]
  unsigned int* ELSd = (unsigned int*)(ws + 3146240);  // [4][8192][64] dwords (8 MB)
  float*  Mg    = ws + 5243392;                     // [32][256][64] (2 MB)
  float*  cs    = ws + 5767680;                     // [32][256]
  bf16_t* clsb  = (bf16_t*)(ws + 5775872);          // [64][512] bf16

  cast_kernel<<<2064, 256, 0, stream>>>(wr, Awr, cls_w, clsb);
  w2_kernel<<<dim3(32, 8), 256, 0, stream>>>(conv_w, clsb, Vt);
  bias2_kernel<<<8, 256, 0, stream>>>(conv_b, cls_w, cls_b, bias2);
  ls_mfma<<<dim3(128, 2), 256, 0, stream>>>(Awr, Vt, bias2, mask, ELSd);
  dp_kernel<<<32, 256, 0, stream>>>(T, Tfb, ELSd, Mg, cs);
  final_kernel<<<32, 64, 0, stream>>>(mask, Tfb, T2e, ELSd, Mg, cs, out);
}